// Round 1
// baseline (242.677 us; speedup 1.0000x reference)
//
#include <hip/hip_runtime.h>

// Problem dims (fixed by the reference):
#define BB 1024
#define AA 25
#define NN 250   // graph_size
#define PP 250   // patrol nodes
#define BA (BB * AA)  // 25600 (b,a) pairs

// One WAVE per (b,a) pair — no LDS, no __syncthreads.
//
// Per (b,a): out row = 250 nodes x 6 floats = 375 float4, 16B-aligned.
// 12-float group g (nodes 2g, 2g+1), q = 3g + r:
//   r=0 : (s[6g+0], s[6g+1], s[6g+2], zx)
//   r=1 : (zy, adj[2g], s[6g+3], s[6g+4])
//   r=2 : (s[6g+5], zx, zy, adj[2g+1])
//
// Stores: op4[q], q = lane + 64*it -> contiguous 1KB per wave-store (perfect).
// Loads: 2-3 scattered dwords/lane within a ~1.5KB window -> L1-served;
//        every state byte still leaves HBM exactly once.
// The nlv -> patrol_index -> coords/adj dependent chain is paid once per
// wave and hidden by 32 independent waves/CU (no barrier coupling).
__global__ __launch_bounds__(256) void policy_kernel(
    const float* __restrict__ state,         // [B*A, N*3]
    const float* __restrict__ nodes_coords,  // [P, 2]
    const float* __restrict__ adj,           // [P, N]
    const int*   __restrict__ nlv,           // [B*A]
    const int*   __restrict__ patrol_index,  // [P]
    float* __restrict__ out)                 // [B*A, N*6]
{
    const int wave = threadIdx.x >> 6;                 // 0..3
    const int lane = threadIdx.x & 63;
    const int ba   = blockIdx.x * 4 + wave;            // grid 6400 * 4 waves = 25600 exact

    // Wave-uniform scalars (same-address loads broadcast; 3-deep chain,
    // hidden by TLP across 32 waves/CU).
    const int nv  = nlv[ba];
    const int idx = patrol_index[nv];
    const float zx = nodes_coords[2 * nv + 0];
    const float zy = nodes_coords[2 * nv + 1];

    const float* __restrict__ st = state + (size_t)ba * (NN * 3);  // 8B-aligned base
    const float* __restrict__ ad = adj   + (size_t)idx * NN;
    float4* __restrict__ op4 = (float4*)(out + (size_t)ba * (NN * 6));  // 16B-aligned

    #pragma unroll
    for (int it = 0; it < 6; ++it) {
        const int q = lane + 64 * it;          // 0..383; iterations 0..4 provably < 375
        if (q < (NN * 6) / 4) {
            const int g  = q / 3;
            const int r  = q - 3 * g;
            const int sb = 6 * g;
            float4 v;
            if (r == 0) {
                v.x = st[sb + 0];
                v.y = st[sb + 1];
                v.z = st[sb + 2];
                v.w = zx;
            } else if (r == 1) {
                v.x = zy;
                v.y = ad[2 * g + 0];
                v.z = st[sb + 3];
                v.w = st[sb + 4];
            } else {
                v.x = st[sb + 5];
                v.y = zx;
                v.z = zy;
                v.w = ad[2 * g + 1];
            }
            op4[q] = v;
        }
    }
}

extern "C" void kernel_launch(void* const* d_in, const int* in_sizes, int n_in,
                              void* d_out, int out_size, void* d_ws, size_t ws_size,
                              hipStream_t stream) {
    const float* state        = (const float*)d_in[0];
    const float* nodes_coords = (const float*)d_in[1];
    const float* adj          = (const float*)d_in[2];
    const int*   nlv          = (const int*)d_in[3];
    const int*   patrol_index = (const int*)d_in[4];
    float* out = (float*)d_out;

    policy_kernel<<<dim3(BA / 4), dim3(256), 0, stream>>>(
        state, nodes_coords, adj, nlv, patrol_index, out);
}

// Round 2
// 221.560 us; speedup vs baseline: 1.0953x; 1.0953x over previous
//
#include <hip/hip_runtime.h>

// Problem dims (fixed by the reference):
#define BB 1024
#define AA 25
#define NN 250   // graph_size
#define PP 250   // patrol nodes
#define BA (BB * AA)  // 25600 (b,a) pairs

// v2: one WAVE per (b,a), wave-private LDS slice, NO __syncthreads.
//
// Wave LDS slice layout (1024 floats = 4 KB):
//   [0..749]    state row (750 f32)
//   [750..999]  adj row   (250 f32)
//   [1000]      zx, [1001] zy
//
// Staging: coalesced float2 loads of state (8B/lane), coalesced dword loads
// of adj. Cross-lane RAW inside the wave is ordered by an explicit
// s_waitcnt lgkmcnt(0) (no barrier needed — single wave).
//
// Epilogue: branchless. out float4 q (q=3g+r) components are ALL ds_read_b32
// at select-computed addresses:
//   r=0: (L[6g],  L[6g+1],   L[6g+2], L[ZX])
//   r=1: (L[ZY],  L[AD+2g],  L[6g+3], L[6g+4])
//   r=2: (L[6g+5],L[ZX],     L[ZY],   L[AD+2g+1])
// Stores: op4[lane + 64*it] -> contiguous 1KB per wave-store, 16B aligned.
#define WSL 1024   // floats per wave slice
#define ADB 750    // adj base within slice
#define ZXI 1000
#define ZYI 1001

__global__ __launch_bounds__(256) void policy_kernel(
    const float* __restrict__ state,         // [B*A, N*3]
    const float* __restrict__ nodes_coords,  // [P, 2]
    const float* __restrict__ adj,           // [P, N]
    const int*   __restrict__ nlv,           // [B*A]
    const int*   __restrict__ patrol_index,  // [P]
    float* __restrict__ out)                 // [B*A, N*6]
{
    __shared__ float s_buf[4 * WSL];  // 16 KB/block, 4 independent wave slices

    const int wave = threadIdx.x >> 6;
    const int lane = threadIdx.x & 63;
    const int ba   = blockIdx.x * 4 + wave;   // 6400 blocks * 4 waves = 25600 exact
    float* L = s_buf + wave * WSL;

    // Wave-uniform scalar chain (broadcast loads); hidden by 32 waves/CU TLP.
    const int nv  = nlv[ba];
    const int idx = patrol_index[nv];
    const float2 z = *(const float2*)(nodes_coords + 2 * nv);

    const float2* __restrict__ st2 = (const float2*)(state + (size_t)ba * (NN * 3));
    const float*  __restrict__ ad  = adj + (size_t)idx * NN;

    // Stage state row: 375 coalesced float2 (iters 0..4 full, 5 partial).
    #pragma unroll
    for (int i = 0; i < 6; ++i) {
        const int j = lane + 64 * i;
        if (j < (NN * 3) / 2) *(float2*)(L + 2 * j) = st2[j];
    }
    // Stage adj row: 250 coalesced dwords.
    #pragma unroll
    for (int i = 0; i < 4; ++i) {
        const int j = lane + 64 * i;
        if (j < NN) L[ADB + j] = ad[j];
    }
    if (lane == 0) { L[ZXI] = z.x; L[ZYI] = z.y; }

    // In-wave LDS RAW fence (no barrier: slice is wave-private).
    asm volatile("s_waitcnt lgkmcnt(0)" ::: "memory");

    float4* __restrict__ op4 = (float4*)(out + (size_t)ba * (NN * 6));

    #pragma unroll
    for (int it = 0; it < 6; ++it) {
        const int q = lane + 64 * it;            // 0..383
        if (q < (NN * 6) / 4) {                  // only it=5 is partial
            const int g  = q / 3;
            const int r  = q - 3 * g;
            const int sb = 6 * g;
            // Branchless per-component LDS addresses.
            const int ax = (r == 0) ? sb     : (r == 1) ? ZYI        : sb + 5;
            const int ay = (r == 0) ? sb + 1 : (r == 1) ? ADB + 2*g  : ZXI;
            const int az = (r == 0) ? sb + 2 : (r == 1) ? sb + 3     : ZYI;
            const int aw = (r == 0) ? ZXI    : (r == 1) ? sb + 4     : ADB + 2*g + 1;
            float4 v;
            v.x = L[ax];
            v.y = L[ay];
            v.z = L[az];
            v.w = L[aw];
            op4[q] = v;
        }
    }
}

extern "C" void kernel_launch(void* const* d_in, const int* in_sizes, int n_in,
                              void* d_out, int out_size, void* d_ws, size_t ws_size,
                              hipStream_t stream) {
    const float* state        = (const float*)d_in[0];
    const float* nodes_coords = (const float*)d_in[1];
    const float* adj          = (const float*)d_in[2];
    const int*   nlv          = (const int*)d_in[3];
    const int*   patrol_index = (const int*)d_in[4];
    float* out = (float*)d_out;

    policy_kernel<<<dim3(BA / 4), dim3(256), 0, stream>>>(
        state, nodes_coords, adj, nlv, patrol_index, out);
}